// Round 1
// baseline (109.292 us; speedup 1.0000x reference)
//
#include <hip/hip_runtime.h>
#include <hip/hip_bf16.h>
#include <math.h>

#define C_DIM 512
#define H_DIM 1024
#define E_NUM 16
#define NTOK  2048
#define NSLOT 4096
#define NROWS 6144
#define BM 64
#define MAXTILES 112

typedef __attribute__((ext_vector_type(8))) short short8;
typedef __attribute__((ext_vector_type(4))) float floatx4;

__device__ __forceinline__ unsigned short f2b(float f){
  unsigned int u = __float_as_uint(f);
  unsigned int r = (u + 0x7FFFu + ((u >> 16) & 1u)) >> 16;
  return (unsigned short)r;
}

// ---- convert x (f32) -> bf16, vectorized ----
__global__ __launch_bounds__(256) void k_cvt_x(const float* __restrict__ x,
                                               unsigned short* __restrict__ xb){
  int i = blockIdx.x * 256 + threadIdx.x;          // quad id, 262144 total
  const float4 v = reinterpret_cast<const float4*>(x)[i];
  ushort4 o;
  o.x = f2b(v.x); o.y = f2b(v.y); o.z = f2b(v.z); o.w = f2b(v.w);
  reinterpret_cast<ushort4*>(xb)[i] = o;
}

// ---- transpose + convert: in f32 [batch][K][N] -> out bf16 [batch][N][K] ----
__global__ __launch_bounds__(256) void k_transpose(const float* __restrict__ in,
                                                   unsigned short* __restrict__ out,
                                                   int K, int N){
  __shared__ float tile[32][33];
  const size_t mat = (size_t)K * N;
  const float* inp = in + mat * blockIdx.z;
  unsigned short* outp = out + mat * blockIdx.z;
  int n0 = blockIdx.x * 32, k0 = blockIdx.y * 32;
  int tx = threadIdx.x & 31, ty = threadIdx.x >> 5;  // ty 0..7
  #pragma unroll
  for (int i = 0; i < 4; i++)
    tile[ty + 8*i][tx] = inp[(size_t)(k0 + ty + 8*i) * N + n0 + tx];
  __syncthreads();
  #pragma unroll
  for (int i = 0; i < 4; i++)
    outp[(size_t)(n0 + ty + 8*i) * K + k0 + tx] = f2b(tile[tx][ty + 8*i]);
}

// ---- router: one wave per token ----
__global__ __launch_bounds__(64) void k_router(const float* __restrict__ x,
                                               const int* __restrict__ op_id,
                                               const float* __restrict__ ekey,
                                               int* __restrict__ gids,
                                               float* __restrict__ w){
  int t = blockIdx.x;
  int lane = threadIdx.x;
  const float* xr = x + (size_t)t * C_DIM;
  float xs[8];
  float xn2 = 0.f;
  #pragma unroll
  for (int i = 0; i < 8; i++){ float v = xr[lane + 64*i]; xs[i] = v; xn2 += v*v; }
  #pragma unroll
  for (int o = 32; o; o >>= 1) xn2 += __shfl_xor(xn2, o, 64);
  int bucket = min(max(op_id[t], 0), 3);
  float xn = fmaxf(sqrtf(xn2), 1e-12f);

  float p[4];
  #pragma unroll
  for (int e = 0; e < 4; e++){
    const float* kr = ekey + ((size_t)bucket * 4 + e) * C_DIM;
    float dot = 0.f, kn2 = 0.f;
    #pragma unroll
    for (int i = 0; i < 8; i++){ float kv = kr[lane + 64*i]; dot += xs[i]*kv; kn2 += kv*kv; }
    #pragma unroll
    for (int o = 32; o; o >>= 1){ dot += __shfl_xor(dot, o, 64); kn2 += __shfl_xor(kn2, o, 64); }
    float kn = fmaxf(sqrtf(kn2), 1e-12f);
    p[e] = dot / (xn * kn);   // tau = 1
  }
  // softmax over 4
  float mx = fmaxf(fmaxf(p[0], p[1]), fmaxf(p[2], p[3]));
  float Z = 0.f;
  #pragma unroll
  for (int e = 0; e < 4; e++){ p[e] = expf(p[e] - mx); Z += p[e]; }
  #pragma unroll
  for (int e = 0; e < 4; e++) p[e] /= Z;
  // top-2, index-order tie-break (matches lax.top_k)
  int i0 = 0;
  #pragma unroll
  for (int e = 1; e < 4; e++) if (p[e] > p[i0]) i0 = e;
  int i1 = (i0 == 0) ? 1 : 0;
  #pragma unroll
  for (int e = 0; e < 4; e++) if (e != i0 && e != i1 && p[e] > p[i1]) i1 = e;
  float v0 = p[i0], v1 = p[i1];
  float ws = v0 + v1 + 1e-9f;
  if (lane == 0){
    gids[2*t]   = bucket * 4 + i0;
    gids[2*t+1] = bucket * 4 + i1;
    w[2*t]   = v0 / ws;
    w[2*t+1] = v1 / ws;
  }
}

// ---- deterministic counting sort of 4096 slots by expert + tile table ----
__global__ __launch_bounds__(256) void k_sort(const int* __restrict__ gids,
                                              int* __restrict__ idx,
                                              int* __restrict__ inv,
                                              int* __restrict__ rowTok,
                                              int* __restrict__ tiles){
  __shared__ int hist[256][16];
  __shared__ int off[17];
  int t = threadIdx.x;
  int h[16];
  #pragma unroll
  for (int e = 0; e < 16; e++) h[e] = 0;
  int base = t * 16;
  for (int s = 0; s < 16; s++){ int g = gids[base + s]; h[g]++; }
  #pragma unroll
  for (int e = 0; e < 16; e++) hist[t][e] = h[e];
  __syncthreads();
  if (t < 16){
    int run = 0;
    for (int i = 0; i < 256; i++){ int v = hist[i][t]; hist[i][t] = run; run += v; }
    off[t + 1] = run;
  }
  __syncthreads();
  if (t == 0){ off[0] = 0; for (int e = 0; e < 16; e++) off[e+1] += off[e]; }
  __syncthreads();
  #pragma unroll
  for (int e = 0; e < 16; e++) h[e] = hist[t][e];
  for (int s = 0; s < 16; s++){
    int slot = base + s;
    int g = gids[slot];
    int pos = off[g] + h[g]; h[g]++;
    idx[pos] = slot;
    inv[slot] = pos;
    rowTok[NTOK + pos] = slot >> 1;
  }
  for (int r = t; r < NTOK; r += 256) rowTok[r] = r;
  __syncthreads();
  if (t == 0){
    int nt = 0;
    for (int r0 = 0; r0 < NTOK; r0 += BM){
      tiles[nt*3] = r0; tiles[nt*3+1] = BM; tiles[nt*3+2] = 16; nt++;
    }
    for (int e = 0; e < 16; e++){
      int c = off[e+1] - off[e];
      for (int r0 = 0; r0 < c; r0 += BM){
        tiles[nt*3] = NTOK + off[e] + r0;
        tiles[nt*3+1] = min(BM, c - r0);
        tiles[nt*3+2] = e;
        nt++;
      }
    }
    for (int i = nt; i < MAXTILES; i++){ tiles[i*3] = 0; tiles[i*3+1] = 0; tiles[i*3+2] = 0; }
  }
}

// ---- grouped GEMM: C[row] = A[row] @ B[eid]^T-stored, fused bias (+relu) ----
// A: bf16 rows (gather via rowTok for GEMM1); Bt: bf16 [N][K]; 64x64 tile, BK=64.
template<int KDIM, int NDIM, bool RELU, bool OUTBF, bool GATHER>
__global__ __launch_bounds__(256) void k_gemm(const unsigned short* __restrict__ A,
                                              const unsigned short* __restrict__ BtE,
                                              const unsigned short* __restrict__ BtS,
                                              const float* __restrict__ biasE,
                                              const float* __restrict__ biasS,
                                              const int* __restrict__ rowTok,
                                              const int* __restrict__ tiles,
                                              unsigned short* __restrict__ outB,
                                              float* __restrict__ outF){
  const int tileId = blockIdx.x;
  const int rows = tiles[tileId*3+1];
  if (rows == 0) return;
  const int row0 = tiles[tileId*3];
  const int eid  = tiles[tileId*3+2];
  const unsigned short* Bt = (eid < 16) ? (BtE + (size_t)eid * NDIM * KDIM) : BtS;
  const float* bias = (eid < 16) ? (biasE + eid * NDIM) : biasS;
  const int n0 = blockIdx.y * 64;

  __shared__ __align__(16) char smem[16384];
  char* As = smem;
  char* Bs = smem + 8192;

  const int tid = threadIdx.x;
  const int lane = tid & 63;
  const int wid = tid >> 6;
  const int wm = wid >> 1, wn = wid & 1;
  const int l15 = lane & 15, lhi = lane >> 4;

  floatx4 acc[2][2] = {};

  for (int kt = 0; kt < KDIM / 64; ++kt){
    #pragma unroll
    for (int c = tid; c < 512; c += 256){
      int i = c >> 3, o = c & 7;
      int ie = min(i, rows - 1);
      size_t arow = GATHER ? (size_t)rowTok[row0 + ie] : (size_t)(row0 + ie);
      const int4 v = *reinterpret_cast<const int4*>(A + arow * KDIM + kt * 64 + o * 8);
      *reinterpret_cast<int4*>(As + i * 128 + ((o * 16) ^ ((i & 7) << 4))) = v;
    }
    #pragma unroll
    for (int c = tid; c < 512; c += 256){
      int i = c >> 3, o = c & 7;
      const int4 v = *reinterpret_cast<const int4*>(Bt + (size_t)(n0 + i) * KDIM + kt * 64 + o * 8);
      *reinterpret_cast<int4*>(Bs + i * 128 + ((o * 16) ^ ((i & 7) << 4))) = v;
    }
    __syncthreads();
    #pragma unroll
    for (int kk = 0; kk < 2; ++kk){
      short8 a[2], b[2];
      #pragma unroll
      for (int m = 0; m < 2; m++){
        int r = wm * 32 + m * 16 + l15;
        a[m] = *reinterpret_cast<const short8*>(As + r * 128 + ((kk * 64 + lhi * 16) ^ ((r & 7) << 4)));
      }
      #pragma unroll
      for (int n = 0; n < 2; n++){
        int r = wn * 32 + n * 16 + l15;
        b[n] = *reinterpret_cast<const short8*>(Bs + r * 128 + ((kk * 64 + lhi * 16) ^ ((r & 7) << 4)));
      }
      #pragma unroll
      for (int m = 0; m < 2; m++)
        #pragma unroll
        for (int n = 0; n < 2; n++)
          acc[m][n] = __builtin_amdgcn_mfma_f32_16x16x32_bf16(a[m], b[n], acc[m][n], 0, 0, 0);
    }
    __syncthreads();
  }
  // epilogue: bias (+relu), store
  #pragma unroll
  for (int m = 0; m < 2; m++){
    #pragma unroll
    for (int n = 0; n < 2; n++){
      int gcol = n0 + wn * 32 + n * 16 + l15;
      float bv = bias[gcol];
      #pragma unroll
      for (int q = 0; q < 4; q++){
        int ri = wm * 32 + m * 16 + lhi * 4 + q;
        if (ri < rows){
          float v = acc[m][n][q] + bv;
          if (RELU) v = fmaxf(v, 0.f);
          size_t o = (size_t)(row0 + ri) * NDIM + gcol;
          if (OUTBF) outB[o] = f2b(v); else outF[o] = v;
        }
      }
    }
  }
}

// ---- combine: y = dense + sigmoid(gate) * (w0*oe0 + w1*oe1) ----
__global__ __launch_bounds__(256) void k_combine(const float* __restrict__ O,
                                                 const float* __restrict__ w,
                                                 const int* __restrict__ inv,
                                                 const float* __restrict__ gate,
                                                 float* __restrict__ y){
  int q = blockIdx.x * 256 + threadIdx.x;   // 262144 quads
  int t = q >> 7, c4 = q & 127;
  float sig = 1.f / (1.f + expf(-gate[0]));
  const float4* Of = reinterpret_cast<const float4*>(O);
  float4 d  = Of[(size_t)t * 128 + c4];
  int p0 = inv[2*t], p1 = inv[2*t+1];
  float w0 = w[2*t], w1 = w[2*t+1];
  float4 o0 = Of[(size_t)(NTOK + p0) * 128 + c4];
  float4 o1 = Of[(size_t)(NTOK + p1) * 128 + c4];
  float4 r;
  r.x = d.x + sig * (w0 * o0.x + w1 * o1.x);
  r.y = d.y + sig * (w0 * o0.y + w1 * o1.y);
  r.z = d.z + sig * (w0 * o0.z + w1 * o1.z);
  r.w = d.w + sig * (w0 * o0.w + w1 * o1.w);
  reinterpret_cast<float4*>(y)[q] = r;
}

extern "C" void kernel_launch(void* const* d_in, const int* in_sizes, int n_in,
                              void* d_out, int out_size, void* d_ws, size_t ws_size,
                              hipStream_t stream){
  const float* x    = (const float*)d_in[0];
  const int*   opid = (const int*)d_in[1];
  const float* ekey = (const float*)d_in[2];
  const float* sW1  = (const float*)d_in[3];
  const float* sb1  = (const float*)d_in[4];
  const float* sW2  = (const float*)d_in[5];
  const float* sb2  = (const float*)d_in[6];
  const float* eW1  = (const float*)d_in[7];
  const float* eb1  = (const float*)d_in[8];
  const float* eW2  = (const float*)d_in[9];
  const float* eb2  = (const float*)d_in[10];
  const float* gate = (const float*)d_in[11];
  float* y = (float*)d_out;

  char* ws = (char*)d_ws;
  size_t off = 0;
  auto alloc = [&](size_t bytes) -> char* {
    char* p = ws + off; off += (bytes + 255) & ~(size_t)255; return p;
  };
  unsigned short* Xb   = (unsigned short*)alloc((size_t)NTOK * C_DIM * 2);
  unsigned short* sW1t = (unsigned short*)alloc((size_t)H_DIM * C_DIM * 2);
  unsigned short* sW2t = (unsigned short*)alloc((size_t)C_DIM * H_DIM * 2);
  unsigned short* eW1t = (unsigned short*)alloc((size_t)E_NUM * H_DIM * C_DIM * 2);
  unsigned short* eW2t = (unsigned short*)alloc((size_t)E_NUM * C_DIM * H_DIM * 2);
  unsigned short* H1   = (unsigned short*)alloc((size_t)NROWS * H_DIM * 2);
  float* O      = (float*)alloc((size_t)NROWS * C_DIM * 4);
  float* wv     = (float*)alloc((size_t)NSLOT * 4);
  int*   gids   = (int*)alloc((size_t)NSLOT * 4);
  int*   idx    = (int*)alloc((size_t)NSLOT * 4);
  int*   inv    = (int*)alloc((size_t)NSLOT * 4);
  int*   rowTok = (int*)alloc((size_t)NROWS * 4);
  int*   tiles  = (int*)alloc((size_t)MAXTILES * 3 * 4);

  k_cvt_x<<<1024, 256, 0, stream>>>(x, Xb);
  k_transpose<<<dim3(H_DIM/32, C_DIM/32, 1), 256, 0, stream>>>(sW1, sW1t, C_DIM, H_DIM);
  k_transpose<<<dim3(C_DIM/32, H_DIM/32, 1), 256, 0, stream>>>(sW2, sW2t, H_DIM, C_DIM);
  k_transpose<<<dim3(H_DIM/32, C_DIM/32, E_NUM), 256, 0, stream>>>(eW1, eW1t, C_DIM, H_DIM);
  k_transpose<<<dim3(C_DIM/32, H_DIM/32, E_NUM), 256, 0, stream>>>(eW2, eW2t, H_DIM, C_DIM);
  k_router<<<NTOK, 64, 0, stream>>>(x, opid, ekey, gids, wv);
  k_sort<<<1, 256, 0, stream>>>(gids, idx, inv, rowTok, tiles);
  k_gemm<C_DIM, H_DIM, true,  true,  true ><<<dim3(MAXTILES, H_DIM/64), 256, 0, stream>>>(
      Xb, eW1t, sW1t, eb1, sb1, rowTok, tiles, H1, nullptr);
  k_gemm<H_DIM, C_DIM, false, false, false><<<dim3(MAXTILES, C_DIM/64), 256, 0, stream>>>(
      H1, eW2t, sW2t, eb2, sb2, rowTok, tiles, nullptr, O);
  k_combine<<<1024, 256, 0, stream>>>(O, wv, inv, gate, y);
}

// Round 2
// 82.302 us; speedup vs baseline: 1.3279x; 1.3279x over previous
//
#include <hip/hip_runtime.h>
#include <hip/hip_bf16.h>
#include <math.h>

#define C_DIM 512
#define H_DIM 1024
#define NTOK  2048
#define NSLOT 4096
#define NROWS 6144
#define MAXT128 64
#define MAXT64  112

typedef __attribute__((ext_vector_type(8))) short short8;
typedef __attribute__((ext_vector_type(4))) float floatx4;
typedef __attribute__((address_space(3))) void as3_void;
typedef const __attribute__((address_space(1))) void as1_cvoid;

__device__ __forceinline__ void gload_lds16(const void* g, void* l){
  __builtin_amdgcn_global_load_lds((as1_cvoid*)g, (as3_void*)l, 16, 0, 0);
}

__device__ __forceinline__ unsigned short f2b(float f){
  unsigned int u = __float_as_uint(f);
  unsigned int r = (u + 0x7FFFu + ((u >> 16) & 1u)) >> 16;
  return (unsigned short)r;
}

// ===== fused prep: x->bf16, router, all weight transposes (f32 [K][N] -> bf16 [N][K]) =====
#define NB_CVT 1024
#define NB_RTR 512
#define NB_T1  2176
#define NB_T2  2176

__global__ __launch_bounds__(256) void k_prep(const float* __restrict__ x,
                                              const int* __restrict__ op_id,
                                              const float* __restrict__ ekey,
                                              const float* __restrict__ sW1,
                                              const float* __restrict__ sW2,
                                              const float* __restrict__ eW1,
                                              const float* __restrict__ eW2,
                                              unsigned short* __restrict__ Xb,
                                              unsigned short* __restrict__ sW1t,
                                              unsigned short* __restrict__ sW2t,
                                              unsigned short* __restrict__ eW1t,
                                              unsigned short* __restrict__ eW2t,
                                              int* __restrict__ gids,
                                              float* __restrict__ wv){
  __shared__ float tile[64 * 65];
  const int bid = blockIdx.x;
  const int tid = threadIdx.x;

  if (bid < NB_CVT){
    int i = bid * 256 + tid;                      // float4 quads, 262144 total
    float4 v = reinterpret_cast<const float4*>(x)[i];
    ushort4 o;
    o.x = f2b(v.x); o.y = f2b(v.y); o.z = f2b(v.z); o.w = f2b(v.w);
    reinterpret_cast<ushort4*>(Xb)[i] = o;
    return;
  }
  if (bid < NB_CVT + NB_RTR){
    // one wave per token, 4 tokens per block
    int t = (bid - NB_CVT) * 4 + (tid >> 6);
    int lane = tid & 63;
    const float* xr = x + (size_t)t * C_DIM;
    float xs[8];
    float xn2 = 0.f;
    #pragma unroll
    for (int i = 0; i < 8; i++){ float v = xr[lane + 64*i]; xs[i] = v; xn2 += v*v; }
    #pragma unroll
    for (int o = 32; o; o >>= 1) xn2 += __shfl_xor(xn2, o, 64);
    int bucket = min(max(op_id[t], 0), 3);
    float xn = fmaxf(sqrtf(xn2), 1e-12f);
    float p[4];
    #pragma unroll
    for (int e = 0; e < 4; e++){
      const float* kr = ekey + ((size_t)bucket * 4 + e) * C_DIM;
      float dot = 0.f, kn2 = 0.f;
      #pragma unroll
      for (int i = 0; i < 8; i++){ float kv = kr[lane + 64*i]; dot += xs[i]*kv; kn2 += kv*kv; }
      #pragma unroll
      for (int o = 32; o; o >>= 1){ dot += __shfl_xor(dot, o, 64); kn2 += __shfl_xor(kn2, o, 64); }
      float kn = fmaxf(sqrtf(kn2), 1e-12f);
      p[e] = dot / (xn * kn);
    }
    float mx = fmaxf(fmaxf(p[0], p[1]), fmaxf(p[2], p[3]));
    float Z = 0.f;
    #pragma unroll
    for (int e = 0; e < 4; e++){ p[e] = expf(p[e] - mx); Z += p[e]; }
    #pragma unroll
    for (int e = 0; e < 4; e++) p[e] /= Z;
    int i0 = 0;
    #pragma unroll
    for (int e = 1; e < 4; e++) if (p[e] > p[i0]) i0 = e;
    int i1 = (i0 == 0) ? 1 : 0;
    #pragma unroll
    for (int e = 0; e < 4; e++) if (e != i0 && e != i1 && p[e] > p[i1]) i1 = e;
    float v0 = p[i0], v1 = p[i1];
    float wsum = v0 + v1 + 1e-9f;
    if (lane == 0){
      gids[2*t]   = bucket * 4 + i0;
      gids[2*t+1] = bucket * 4 + i1;
      wv[2*t]   = v0 / wsum;
      wv[2*t+1] = v1 / wsum;
    }
    return;
  }

  // transpose branches
  const float* in; unsigned short* out;
  int K, N, n0, k0;
  if (bid < NB_CVT + NB_RTR + NB_T1){
    int tb = bid - (NB_CVT + NB_RTR);
    int mat = tb >> 7, tl = tb & 127;
    K = C_DIM; N = H_DIM;                          // 512 x 1024, tiles 16 x 8
    in  = (mat < 16) ? eW1 + (size_t)mat * K * N : sW1;
    out = (mat < 16) ? eW1t + (size_t)mat * K * N : sW1t;
    n0 = (tl & 15) * 64; k0 = (tl >> 4) * 64;
  } else {
    int tb = bid - (NB_CVT + NB_RTR + NB_T1);
    int mat = tb >> 7, tl = tb & 127;
    K = H_DIM; N = C_DIM;                          // 1024 x 512, tiles 8 x 16
    in  = (mat < 16) ? eW2 + (size_t)mat * K * N : sW2;
    out = (mat < 16) ? eW2t + (size_t)mat * K * N : sW2t;
    n0 = (tl & 7) * 64; k0 = (tl >> 3) * 64;
  }
  {
    int tx = tid & 15, ty = tid >> 4;              // read: 16 lanes x float4 = 64 cols
    #pragma unroll
    for (int i = 0; i < 4; i++){
      int k = ty + 16 * i;
      float4 v = *reinterpret_cast<const float4*>(in + (size_t)(k0 + k) * N + n0 + tx * 4);
      tile[k * 65 + tx * 4 + 0] = v.x;
      tile[k * 65 + tx * 4 + 1] = v.y;
      tile[k * 65 + tx * 4 + 2] = v.z;
      tile[k * 65 + tx * 4 + 3] = v.w;
    }
    __syncthreads();
    #pragma unroll
    for (int i = 0; i < 4; i++){
      int n = ty + 16 * i;
      ushort4 o;
      o.x = f2b(tile[(4*tx + 0) * 65 + n]);
      o.y = f2b(tile[(4*tx + 1) * 65 + n]);
      o.z = f2b(tile[(4*tx + 2) * 65 + n]);
      o.w = f2b(tile[(4*tx + 3) * 65 + n]);
      *reinterpret_cast<ushort4*>(out + (size_t)(n0 + n) * K + k0 + 4 * tx) = o;
    }
  }
}

// ===== deterministic counting sort by expert + two tile tables (BM=128 and BM=64) =====
__global__ __launch_bounds__(256) void k_sort(const int* __restrict__ gids,
                                              int* __restrict__ inv,
                                              int* __restrict__ rowTok,
                                              int* __restrict__ tiles128,
                                              int* __restrict__ tiles64){
  __shared__ int hist[256][16];
  __shared__ int off[17];
  int t = threadIdx.x;
  int h[16];
  #pragma unroll
  for (int e = 0; e < 16; e++) h[e] = 0;
  int base = t * 16;
  for (int s = 0; s < 16; s++){ int g = gids[base + s]; h[g]++; }
  #pragma unroll
  for (int e = 0; e < 16; e++) hist[t][e] = h[e];
  __syncthreads();
  if (t < 16){
    int run = 0;
    for (int i = 0; i < 256; i++){ int v = hist[i][t]; hist[i][t] = run; run += v; }
    off[t + 1] = run;
  }
  __syncthreads();
  if (t == 0){ off[0] = 0; for (int e = 0; e < 16; e++) off[e+1] += off[e]; }
  __syncthreads();
  #pragma unroll
  for (int e = 0; e < 16; e++) h[e] = hist[t][e];
  for (int s = 0; s < 16; s++){
    int slot = base + s;
    int g = gids[slot];
    int pos = off[g] + h[g]; h[g]++;
    inv[slot] = pos;
    rowTok[NTOK + pos] = slot >> 1;
  }
  for (int r = t; r < NTOK; r += 256) rowTok[r] = r;
  __syncthreads();
  if (t == 0){
    int nt = 0;
    for (int r0 = 0; r0 < NTOK; r0 += 128){
      tiles128[nt*3] = r0; tiles128[nt*3+1] = 128; tiles128[nt*3+2] = 16; nt++;
    }
    for (int e = 0; e < 16; e++){
      int c = off[e+1] - off[e];
      for (int r0 = 0; r0 < c; r0 += 128){
        tiles128[nt*3] = NTOK + off[e] + r0;
        tiles128[nt*3+1] = min(128, c - r0);
        tiles128[nt*3+2] = e;
        nt++;
      }
    }
    for (int i = nt; i < MAXT128; i++){ tiles128[i*3] = 0; tiles128[i*3+1] = 0; tiles128[i*3+2] = 0; }
    nt = 0;
    for (int r0 = 0; r0 < NTOK; r0 += 64){
      tiles64[nt*3] = r0; tiles64[nt*3+1] = 64; tiles64[nt*3+2] = 16; nt++;
    }
    for (int e = 0; e < 16; e++){
      int c = off[e+1] - off[e];
      for (int r0 = 0; r0 < c; r0 += 64){
        tiles64[nt*3] = NTOK + off[e] + r0;
        tiles64[nt*3+1] = min(64, c - r0);
        tiles64[nt*3+2] = e;
        nt++;
      }
    }
    for (int i = nt; i < MAXT64; i++){ tiles64[i*3] = 0; tiles64[i*3+1] = 0; tiles64[i*3+2] = 0; }
  }
}

// ===== grouped GEMM, BMT x 128 tile, BK=64, 4 waves (2x2), global_load_lds staging =====
// LDS layout: chunk (i,o') at byte i*128 + o'*16 holds element chunk o = o' ^ (i&7)
// (pre-swizzled global source, linear LDS dest -> swizzled ds_read_b128, no bank conflicts)
template<int BMT, int KDIM, int NDIM, bool RELU, bool OUTBF, bool GATHER>
__global__ __launch_bounds__(256) void k_gemm(const unsigned short* __restrict__ A,
                                              const unsigned short* __restrict__ BtE,
                                              const unsigned short* __restrict__ BtS,
                                              const float* __restrict__ biasE,
                                              const float* __restrict__ biasS,
                                              const int* __restrict__ rowTok,
                                              const int* __restrict__ tiles,
                                              unsigned short* __restrict__ outB,
                                              float* __restrict__ outF){
  const int tileId = blockIdx.x;
  const int rows = tiles[tileId*3+1];
  if (rows == 0) return;
  const int row0 = tiles[tileId*3];
  const int eid  = tiles[tileId*3+2];
  const unsigned short* Bt = (eid < 16) ? (BtE + (size_t)eid * NDIM * KDIM) : BtS;
  const float* bias = (eid < 16) ? (biasE + eid * NDIM) : biasS;
  const int n0 = blockIdx.y * 128;

  constexpr int MREP = BMT / 32;          // m-frags per wave (wave covers BMT/2 rows)
  constexpr int AISS = BMT * 8 / 256;     // A staging issues per thread

  __shared__ __align__(16) unsigned short As[BMT * 64];
  __shared__ __align__(16) unsigned short Bs[128 * 64];

  const int tid = threadIdx.x;
  const int lane = tid & 63;
  const int wid = tid >> 6;
  const int wm = wid >> 1, wn = wid & 1;
  const int l15 = lane & 15, lhi = lane >> 4;

  int aRow[AISS], aOff[AISS];
  #pragma unroll
  for (int j = 0; j < AISS; j++){
    int c = j * 256 + tid;
    int i = c >> 3, op = c & 7;
    int o = op ^ (i & 7);
    int ie = min(i, rows - 1);
    aRow[j] = GATHER ? rowTok[row0 + ie] : (row0 + ie);
    aOff[j] = o * 8;
  }
  int bRow[4], bOff[4];
  #pragma unroll
  for (int j = 0; j < 4; j++){
    int c = j * 256 + tid;
    int i = c >> 3, op = c & 7;
    int o = op ^ (i & 7);
    bRow[j] = n0 + i;
    bOff[j] = o * 8;
  }

  floatx4 acc[MREP][4] = {};

  for (int kt = 0; kt < KDIM / 64; ++kt){
    #pragma unroll
    for (int j = 0; j < AISS; j++)
      gload_lds16(A + (size_t)aRow[j] * KDIM + kt * 64 + aOff[j],
                  (char*)As + (j * 256 + tid) * 16);
    #pragma unroll
    for (int j = 0; j < 4; j++)
      gload_lds16(Bt + (size_t)bRow[j] * KDIM + kt * 64 + bOff[j],
                  (char*)Bs + (j * 256 + tid) * 16);
    __syncthreads();
    #pragma unroll
    for (int kk = 0; kk < 2; ++kk){
      short8 a[MREP], b[4];
      #pragma unroll
      for (int m = 0; m < MREP; m++){
        int r = wm * (BMT/2) + m * 16 + l15;
        a[m] = *reinterpret_cast<const short8*>(
            (char*)As + r * 128 + ((kk * 64 + lhi * 16) ^ ((r & 7) << 4)));
      }
      #pragma unroll
      for (int n = 0; n < 4; n++){
        int r = wn * 64 + n * 16 + l15;
        b[n] = *reinterpret_cast<const short8*>(
            (char*)Bs + r * 128 + ((kk * 64 + lhi * 16) ^ ((r & 7) << 4)));
      }
      #pragma unroll
      for (int m = 0; m < MREP; m++)
        #pragma unroll
        for (int n = 0; n < 4; n++)
          acc[m][n] = __builtin_amdgcn_mfma_f32_16x16x32_bf16(a[m], b[n], acc[m][n], 0, 0, 0);
    }
    __syncthreads();
  }

  #pragma unroll
  for (int m = 0; m < MREP; m++){
    #pragma unroll
    for (int n = 0; n < 4; n++){
      int gcol = n0 + wn * 64 + n * 16 + l15;
      float bv = bias[gcol];
      #pragma unroll
      for (int q = 0; q < 4; q++){
        int ri = wm * (BMT/2) + m * 16 + lhi * 4 + q;
        if (ri < rows){
          float v = acc[m][n][q] + bv;
          if (RELU) v = fmaxf(v, 0.f);
          size_t o = (size_t)(row0 + ri) * NDIM + gcol;
          if (OUTBF) outB[o] = f2b(v); else outF[o] = v;
        }
      }
    }
  }
}

// ===== combine: y = dense + sigmoid(gate) * (w0*oe0 + w1*oe1) =====
__global__ __launch_bounds__(256) void k_combine(const float* __restrict__ O,
                                                 const float* __restrict__ w,
                                                 const int* __restrict__ inv,
                                                 const float* __restrict__ gate,
                                                 float* __restrict__ y){
  int q = blockIdx.x * 256 + threadIdx.x;   // 262144 quads
  int t = q >> 7, c4 = q & 127;
  float sig = 1.f / (1.f + expf(-gate[0]));
  const float4* Of = reinterpret_cast<const float4*>(O);
  float4 d  = Of[(size_t)t * 128 + c4];
  int p0 = inv[2*t], p1 = inv[2*t+1];
  float w0 = w[2*t], w1 = w[2*t+1];
  float4 o0 = Of[(size_t)(NTOK + p0) * 128 + c4];
  float4 o1 = Of[(size_t)(NTOK + p1) * 128 + c4];
  float4 r;
  r.x = d.x + sig * (w0 * o0.x + w1 * o1.x);
  r.y = d.y + sig * (w0 * o0.y + w1 * o1.y);
  r.z = d.z + sig * (w0 * o0.z + w1 * o1.z);
  r.w = d.w + sig * (w0 * o0.w + w1 * o1.w);
  reinterpret_cast<float4*>(y)[q] = r;
}

extern "C" void kernel_launch(void* const* d_in, const int* in_sizes, int n_in,
                              void* d_out, int out_size, void* d_ws, size_t ws_size,
                              hipStream_t stream){
  const float* x    = (const float*)d_in[0];
  const int*   opid = (const int*)d_in[1];
  const float* ekey = (const float*)d_in[2];
  const float* sW1  = (const float*)d_in[3];
  const float* sb1  = (const float*)d_in[4];
  const float* sW2  = (const float*)d_in[5];
  const float* sb2  = (const float*)d_in[6];
  const float* eW1  = (const float*)d_in[7];
  const float* eb1  = (const float*)d_in[8];
  const float* eW2  = (const float*)d_in[9];
  const float* eb2  = (const float*)d_in[10];
  const float* gate = (const float*)d_in[11];
  float* y = (float*)d_out;

  char* ws = (char*)d_ws;
  size_t off = 0;
  auto alloc = [&](size_t bytes) -> char* {
    char* p = ws + off; off += (bytes + 255) & ~(size_t)255; return p;
  };
  unsigned short* Xb   = (unsigned short*)alloc((size_t)NTOK * C_DIM * 2);
  unsigned short* sW1t = (unsigned short*)alloc((size_t)H_DIM * C_DIM * 2);
  unsigned short* sW2t = (unsigned short*)alloc((size_t)C_DIM * H_DIM * 2);
  unsigned short* eW1t = (unsigned short*)alloc((size_t)16 * H_DIM * C_DIM * 2);
  unsigned short* eW2t = (unsigned short*)alloc((size_t)16 * C_DIM * H_DIM * 2);
  unsigned short* H1   = (unsigned short*)alloc((size_t)NROWS * H_DIM * 2);
  float* O      = (float*)alloc((size_t)NROWS * C_DIM * 4);
  float* wv     = (float*)alloc((size_t)NSLOT * 4);
  int*   gids   = (int*)alloc((size_t)NSLOT * 4);
  int*   inv    = (int*)alloc((size_t)NSLOT * 4);
  int*   rowTok = (int*)alloc((size_t)NROWS * 4);
  int*   tiles128 = (int*)alloc((size_t)MAXT128 * 3 * 4);
  int*   tiles64  = (int*)alloc((size_t)MAXT64 * 3 * 4);

  k_prep<<<NB_CVT + NB_RTR + NB_T1 + NB_T2, 256, 0, stream>>>(
      x, opid, ekey, sW1, sW2, eW1, eW2, Xb, sW1t, sW2t, eW1t, eW2t, gids, wv);
  k_sort<<<1, 256, 0, stream>>>(gids, inv, rowTok, tiles128, tiles64);
  k_gemm<128, C_DIM, H_DIM, true,  true,  true ><<<dim3(MAXT128, H_DIM/128), 256, 0, stream>>>(
      Xb, eW1t, sW1t, eb1, sb1, rowTok, tiles128, H1, nullptr);
  k_gemm<64,  H_DIM, C_DIM, false, false, false><<<dim3(MAXT64, C_DIM/128), 256, 0, stream>>>(
      H1, eW2t, sW2t, eb2, sb2, rowTok, tiles64, nullptr, O);
  k_combine<<<1024, 256, 0, stream>>>(O, wv, inv, gate, y);
}